// Round 3
// baseline (2788.915 us; speedup 1.0000x reference)
//
#include <hip/hip_runtime.h>

#define N_NODES 100000
#define N_EDGES 1600000
#define D 128
#define NBUCK 782           // ceil(N_NODES / 128)

typedef __attribute__((ext_vector_type(8))) short short8v;
typedef __attribute__((ext_vector_type(4))) float f32x4;

__device__ __forceinline__ unsigned short f2bf(float f) {
    unsigned int u = __float_as_uint(f);
    unsigned int r = (u + 0x7fffu + ((u >> 16) & 1u)) >> 16;
    return (unsigned short)r;
}
__device__ __forceinline__ float bf2f(unsigned int lo16) {
    return __uint_as_float(lo16 << 16);
}
__device__ __forceinline__ short8v zero8() {
    short8v z = {0, 0, 0, 0, 0, 0, 0, 0};
    return z;
}

// ---------------- coarse bucketing (by dst >> 7) ----------------

__global__ void k_bcount(const int* __restrict__ dst, int* __restrict__ bcnt) {
    __shared__ int h[NBUCK];
    for (int i = threadIdx.x; i < NBUCK; i += 256) h[i] = 0;
    __syncthreads();
    int stride = gridDim.x * 256;
    for (int e = blockIdx.x * 256 + threadIdx.x; e < N_EDGES; e += stride)
        atomicAdd(&h[dst[e] >> 7], 1);
    __syncthreads();
    for (int i = threadIdx.x; i < NBUCK; i += 256)
        if (h[i]) atomicAdd(&bcnt[i], h[i]);
}

// single block, 1024 threads: exclusive scan of bcnt -> bstart, bcursor
__global__ void k_bscan(const int* __restrict__ bcnt, int* __restrict__ bstart,
                        int* __restrict__ bcursor) {
    __shared__ int s[1024];
    int t = threadIdx.x;
    int v = (t < NBUCK) ? bcnt[t] : 0;
    s[t] = v;
    __syncthreads();
    for (int o = 1; o < 1024; o <<= 1) {
        int x = (t >= o) ? s[t - o] : 0;
        __syncthreads();
        s[t] += x;
        __syncthreads();
    }
    if (t < NBUCK) {
        bstart[t] = s[t] - v;
        bcursor[t] = s[t] - v;
    }
    if (t == 0) bstart[NBUCK] = N_EDGES;
}

// scatter edges into bucket order; payload = (dst&127)<<17 | src
__global__ __launch_bounds__(256) void k_bscatter(const int* __restrict__ src,
                                                  const int* __restrict__ dst,
                                                  int* __restrict__ bcursor,
                                                  unsigned int* __restrict__ ebuf) {
    __shared__ int cnt[NBUCK];
    __shared__ int base[NBUCK];
    const int t = threadIdx.x;
    const int e0 = blockIdx.x * 4096;
    for (int i = t; i < NBUCK; i += 256) cnt[i] = 0;
    __syncthreads();
#pragma unroll
    for (int u = 0; u < 16; ++u) {
        int e = e0 + u * 256 + t;
        if (e < N_EDGES) atomicAdd(&cnt[dst[e] >> 7], 1);
    }
    __syncthreads();
    for (int i = t; i < NBUCK; i += 256) {
        int c = cnt[i];
        base[i] = c ? atomicAdd(&bcursor[i], c) : 0;
        cnt[i] = 0;
    }
    __syncthreads();
#pragma unroll
    for (int u = 0; u < 16; ++u) {
        int e = e0 + u * 256 + t;
        if (e < N_EDGES) {
            int d = dst[e];
            int b = d >> 7;
            int pos = base[b] + atomicAdd(&cnt[b], 1);
            ebuf[pos] = ((unsigned int)(d & 127) << 17) | (unsigned int)src[e];
        }
    }
}

// per-bucket degree -> inv_deg
__global__ void k_deg(const unsigned int* __restrict__ ebuf, const int* __restrict__ bstart,
                      float* __restrict__ inv_deg) {
    __shared__ int h[128];
    const int b = blockIdx.x;
    const int t = threadIdx.x;
    if (t < 128) h[t] = 0;
    __syncthreads();
    const int e1 = bstart[b + 1];
    for (int e = bstart[b] + t; e < e1; e += 256)
        atomicAdd(&h[ebuf[e] >> 17], 1);
    __syncthreads();
    if (t < 128) {
        int node = b * 128 + t;
        if (node < N_NODES) inv_deg[node] = 1.0f / (float)max(h[t], 1);
    }
}

// ---------------- casts / weight packing ----------------

__global__ void k_cast_bf16(const float* __restrict__ in, unsigned short* __restrict__ out) {
    int i = blockIdx.x * blockDim.x + threadIdx.x;
    float4 v = *(const float4*)&in[(size_t)i * 4];
    uint2 o;
    o.x = (unsigned int)f2bf(v.x) | ((unsigned int)f2bf(v.y) << 16);
    o.y = (unsigned int)f2bf(v.z) | ((unsigned int)f2bf(v.w) << 16);
    *(uint2*)&out[(size_t)i * 4] = o;
}

__global__ void k_pack_w(const float* __restrict__ Wl, const float* __restrict__ Wr,
                         unsigned short* __restrict__ Wcat) {
    int idx = blockIdx.x * blockDim.x + threadIdx.x;
    float v = (idx < 16384) ? Wl[idx] : Wr[idx - 16384];
    Wcat[idx] = f2bf(v);
}

// ---------------- fused bf16 MFMA GEMM: [N x 128] @ [128 x 256] ----------------
template <bool OUT_F32>
__global__ __launch_bounds__(256) void k_gemm_mfma(
    const unsigned short* __restrict__ A,
    const unsigned short* __restrict__ Bt,
    const float* __restrict__ bias,
    unsigned short* __restrict__ Tout,
    void* __restrict__ Hout)
{
    const int wid = threadIdx.x >> 6;
    const int lane = threadIdx.x & 63;
    const int l15 = lane & 15, lg = lane >> 4;
    const int col_base = wid * 64;

    short8v bfrag[4][4];
#pragma unroll
    for (int cg = 0; cg < 4; ++cg)
#pragma unroll
        for (int ks = 0; ks < 4; ++ks)
            bfrag[cg][ks] = *(const short8v*)&Bt[(size_t)(col_base + cg * 16 + l15) * 128
                                                 + ks * 32 + lg * 8];
    float bv[4];
#pragma unroll
    for (int cg = 0; cg < 4; ++cg)
        bv[cg] = (wid >= 2) ? bias[(wid - 2) * 64 + cg * 16 + l15] : 0.0f;

    const int ntiles = (N_NODES + 63) / 64;
    for (int tile = blockIdx.x; tile < ntiles; tile += gridDim.x) {
        const int row0 = tile * 64;
        f32x4 acc[4][4];
#pragma unroll
        for (int rg = 0; rg < 4; ++rg)
#pragma unroll
            for (int cg = 0; cg < 4; ++cg)
                acc[rg][cg] = (f32x4){0.f, 0.f, 0.f, 0.f};

#pragma unroll
        for (int rg = 0; rg < 4; ++rg) {
            const int arow = row0 + rg * 16 + l15;
            short8v afrag[4];
            if (arow < N_NODES) {
#pragma unroll
                for (int ks = 0; ks < 4; ++ks)
                    afrag[ks] = *(const short8v*)&A[(size_t)arow * 128 + ks * 32 + lg * 8];
            } else {
#pragma unroll
                for (int ks = 0; ks < 4; ++ks) afrag[ks] = zero8();
            }
#pragma unroll
            for (int cg = 0; cg < 4; ++cg)
#pragma unroll
                for (int ks = 0; ks < 4; ++ks)
                    acc[rg][cg] = __builtin_amdgcn_mfma_f32_16x16x32_bf16(
                        afrag[ks], bfrag[cg][ks], acc[rg][cg], 0, 0, 0);
        }

        if (wid < 2) {
#pragma unroll
            for (int rg = 0; rg < 4; ++rg) {
                const int rbase = row0 + rg * 16 + lg * 4;
#pragma unroll
                for (int cg = 0; cg < 4; ++cg) {
                    const int col = col_base + cg * 16 + l15;
#pragma unroll
                    for (int i = 0; i < 4; ++i) {
                        int row = rbase + i;
                        if (row < N_NODES)
                            Tout[(size_t)row * 128 + col] = f2bf(acc[rg][cg][i]);
                    }
                }
            }
        } else {
#pragma unroll
            for (int rg = 0; rg < 4; ++rg) {
                const int rbase = row0 + rg * 16 + lg * 4;
#pragma unroll
                for (int cg = 0; cg < 4; ++cg) {
                    const int col = (wid - 2) * 64 + cg * 16 + l15;
#pragma unroll
                    for (int i = 0; i < 4; ++i) {
                        int row = rbase + i;
                        if (row < N_NODES) {
                            float v = acc[rg][cg][i] + bv[cg];
                            if (OUT_F32)
                                ((float*)Hout)[(size_t)row * 128 + col] = v;
                            else
                                ((unsigned short*)Hout)[(size_t)row * 128 + col] = f2bf(v);
                        }
                    }
                }
            }
        }
    }
}

// ---------------- bucket aggregation: LDS accumulate, fused mean+root+(relu) ----------------
// one block (8 waves) per bucket; acc[128 nodes][128 dims] f32 in LDS (64KB).
template <bool RELU, bool IOF32>
__global__ __launch_bounds__(512) void k_agg_bucket(
    const unsigned short* __restrict__ t_mat,   // [N][128] bf16
    const unsigned int* __restrict__ ebuf,
    const int* __restrict__ bstart,
    const float* __restrict__ inv_deg,
    void* __restrict__ io)                       // bf16 or f32, in-place update
{
    __shared__ float acc[128 * 128];             // 64KB
    const int b = blockIdx.x;
    const int t = threadIdx.x;
    const int wid = t >> 6;
    const int lane = t & 63;

    for (int i = t; i < 128 * 32; i += 512)
        *(f32x4*)&acc[i * 4] = (f32x4){0.f, 0.f, 0.f, 0.f};
    __syncthreads();

    const int e1 = bstart[b + 1];
    int e = bstart[b] + wid;
    for (; e + 8 < e1; e += 16) {
        unsigned int pk0 = ebuf[e];
        unsigned int pk1 = ebuf[e + 8];
        int dl0 = pk0 >> 17, s0 = pk0 & 0x1ffff;
        int dl1 = pk1 >> 17, s1 = pk1 & 0x1ffff;
        unsigned int v0 = *(const unsigned int*)&t_mat[(size_t)s0 * 128 + lane * 2];
        unsigned int v1 = *(const unsigned int*)&t_mat[(size_t)s1 * 128 + lane * 2];
        atomicAdd(&acc[dl0 * 128 + lane * 2], bf2f(v0 & 0xffffu));
        atomicAdd(&acc[dl0 * 128 + lane * 2 + 1], __uint_as_float(v0 & 0xffff0000u));
        atomicAdd(&acc[dl1 * 128 + lane * 2], bf2f(v1 & 0xffffu));
        atomicAdd(&acc[dl1 * 128 + lane * 2 + 1], __uint_as_float(v1 & 0xffff0000u));
    }
    if (e < e1) {
        unsigned int pk = ebuf[e];
        int dl = pk >> 17, s = pk & 0x1ffff;
        unsigned int v = *(const unsigned int*)&t_mat[(size_t)s * 128 + lane * 2];
        atomicAdd(&acc[dl * 128 + lane * 2], bf2f(v & 0xffffu));
        atomicAdd(&acc[dl * 128 + lane * 2 + 1], __uint_as_float(v & 0xffff0000u));
    }
    __syncthreads();

    // writeout: i indexes float4 groups (4096 of them)
    for (int i = t; i < 4096; i += 512) {
        int row = i >> 5, c4 = (i & 31) * 4;
        int node = b * 128 + row;
        if (node >= N_NODES) break;
        float inv = inv_deg[node];
        f32x4 a = *(f32x4*)&acc[row * 128 + c4];
        if (IOF32) {
            float* o = (float*)io + (size_t)node * 128 + c4;
            float4 h = *(float4*)o;
            float4 r;
            r.x = h.x + inv * a[0]; r.y = h.y + inv * a[1];
            r.z = h.z + inv * a[2]; r.w = h.w + inv * a[3];
            if (RELU) {
                r.x = fmaxf(r.x, 0.f); r.y = fmaxf(r.y, 0.f);
                r.z = fmaxf(r.z, 0.f); r.w = fmaxf(r.w, 0.f);
            }
            *(float4*)o = r;
        } else {
            unsigned short* o = (unsigned short*)io + (size_t)node * 128 + c4;
            uint2 h = *(uint2*)o;
            float r0 = bf2f(h.x & 0xffffu) + inv * a[0];
            float r1 = __uint_as_float(h.x & 0xffff0000u) + inv * a[1];
            float r2 = bf2f(h.y & 0xffffu) + inv * a[2];
            float r3 = __uint_as_float(h.y & 0xffff0000u) + inv * a[3];
            if (RELU) {
                r0 = fmaxf(r0, 0.f); r1 = fmaxf(r1, 0.f);
                r2 = fmaxf(r2, 0.f); r3 = fmaxf(r3, 0.f);
            }
            uint2 w;
            w.x = (unsigned int)f2bf(r0) | ((unsigned int)f2bf(r1) << 16);
            w.y = (unsigned int)f2bf(r2) | ((unsigned int)f2bf(r3) << 16);
            *(uint2*)o = w;
        }
    }
}

// ---------------- launch ----------------

extern "C" void kernel_launch(void* const* d_in, const int* in_sizes, int n_in,
                              void* d_out, int out_size, void* d_ws, size_t ws_size,
                              hipStream_t stream) {
    const float* x   = (const float*)d_in[0];
    const int*   ei  = (const int*)d_in[1];
    const float* W1l = (const float*)d_in[2];
    const float* W1r = (const float*)d_in[3];
    const float* b1  = (const float*)d_in[4];
    const float* W2l = (const float*)d_in[5];
    const float* W2r = (const float*)d_in[6];
    const float* b2  = (const float*)d_in[7];
    float* out = (float*)d_out;

    const int* src = ei;
    const int* dst = ei + N_EDGES;

    char* p = (char*)d_ws;
    auto alloc = [&](size_t bytes) {
        char* r = p;
        p += (bytes + 255) & ~(size_t)255;
        return r;
    };
    unsigned short* xb = (unsigned short*)alloc((size_t)N_NODES * D * 2);
    unsigned short* tb = (unsigned short*)alloc((size_t)N_NODES * D * 2);
    unsigned short* hx = (unsigned short*)alloc((size_t)N_NODES * D * 2);
    unsigned int*   ebuf    = (unsigned int*)alloc((size_t)N_EDGES * 4);
    int*   bcnt    = (int*)alloc((NBUCK + 1) * sizeof(int));
    int*   bstart  = (int*)alloc((NBUCK + 1) * sizeof(int));
    int*   bcursor = (int*)alloc((NBUCK + 1) * sizeof(int));
    float* inv_deg = (float*)alloc((size_t)N_NODES * sizeof(float));
    unsigned short* wc1 = (unsigned short*)alloc(256 * 128 * 2);
    unsigned short* wc2 = (unsigned short*)alloc(256 * 128 * 2);

    // bucket build
    hipMemsetAsync(bcnt, 0, NBUCK * sizeof(int), stream);
    k_bcount<<<400, 256, 0, stream>>>(dst, bcnt);
    k_bscan<<<1, 1024, 0, stream>>>(bcnt, bstart, bcursor);
    k_bscatter<<<(N_EDGES + 4095) / 4096, 256, 0, stream>>>(src, dst, bcursor, ebuf);
    k_deg<<<NBUCK, 256, 0, stream>>>(ebuf, bstart, inv_deg);

    // casts + weight packing
    k_cast_bf16<<<(N_NODES * D / 4 + 255) / 256, 256, 0, stream>>>(x, xb);
    k_pack_w<<<128, 256, 0, stream>>>(W1l, W1r, wc1);
    k_pack_w<<<128, 256, 0, stream>>>(W2l, W2r, wc2);

    // layer 1
    k_gemm_mfma<false><<<640, 256, 0, stream>>>(xb, wc1, b1, tb, hx);
    k_agg_bucket<true, false><<<NBUCK, 512, 0, stream>>>(tb, ebuf, bstart, inv_deg, hx);

    // layer 2
    k_gemm_mfma<true><<<640, 256, 0, stream>>>(hx, wc2, b2, tb, out);
    k_agg_bucket<false, true><<<NBUCK, 512, 0, stream>>>(tb, ebuf, bstart, inv_deg, out);
}

// Round 4
// 269.877 us; speedup vs baseline: 10.3340x; 10.3340x over previous
//
#include <hip/hip_runtime.h>

#define N_NODES 100000
#define N_EDGES 1600000
#define D 128
#define NBUCK 782           // ceil(N_NODES / 128)

typedef __attribute__((ext_vector_type(8))) short short8v;
typedef __attribute__((ext_vector_type(4))) float f32x4;

__device__ __forceinline__ unsigned short f2bf(float f) {
    unsigned int u = __float_as_uint(f);
    unsigned int r = (u + 0x7fffu + ((u >> 16) & 1u)) >> 16;
    return (unsigned short)r;
}
__device__ __forceinline__ float bf2f(unsigned int lo16) {
    return __uint_as_float(lo16 << 16);
}
__device__ __forceinline__ short8v zero8() {
    short8v z = {0, 0, 0, 0, 0, 0, 0, 0};
    return z;
}

// ---------------- coarse bucketing (by dst >> 7) ----------------

__global__ void k_bcount(const int* __restrict__ dst, int* __restrict__ bcnt) {
    __shared__ int h[NBUCK];
    for (int i = threadIdx.x; i < NBUCK; i += 256) h[i] = 0;
    __syncthreads();
    int stride = gridDim.x * 256;
    for (int e = blockIdx.x * 256 + threadIdx.x; e < N_EDGES; e += stride)
        atomicAdd(&h[dst[e] >> 7], 1);
    __syncthreads();
    for (int i = threadIdx.x; i < NBUCK; i += 256)
        if (h[i]) atomicAdd(&bcnt[i], h[i]);
}

// single block, 1024 threads: exclusive scan of bcnt -> bstart, bcursor
__global__ void k_bscan(const int* __restrict__ bcnt, int* __restrict__ bstart,
                        int* __restrict__ bcursor, int* __restrict__ row_start) {
    __shared__ int s[1024];
    int t = threadIdx.x;
    int v = (t < NBUCK) ? bcnt[t] : 0;
    s[t] = v;
    __syncthreads();
    for (int o = 1; o < 1024; o <<= 1) {
        int x = (t >= o) ? s[t - o] : 0;
        __syncthreads();
        s[t] += x;
        __syncthreads();
    }
    if (t < NBUCK) {
        bstart[t] = s[t] - v;
        bcursor[t] = s[t] - v;
    }
    if (t == 0) {
        bstart[NBUCK] = N_EDGES;
        row_start[NBUCK * 128] = N_EDGES;
    }
}

// scatter edges into coarse-bucket order; payload = (dst&127)<<17 | src
__global__ __launch_bounds__(256) void k_bscatter(const int* __restrict__ src,
                                                  const int* __restrict__ dst,
                                                  int* __restrict__ bcursor,
                                                  unsigned int* __restrict__ ebuf) {
    __shared__ int cnt[NBUCK];
    __shared__ int base[NBUCK];
    const int t = threadIdx.x;
    const int e0 = blockIdx.x * 4096;
    for (int i = t; i < NBUCK; i += 256) cnt[i] = 0;
    __syncthreads();
#pragma unroll
    for (int u = 0; u < 16; ++u) {
        int e = e0 + u * 256 + t;
        if (e < N_EDGES) atomicAdd(&cnt[dst[e] >> 7], 1);
    }
    __syncthreads();
    for (int i = t; i < NBUCK; i += 256) {
        int c = cnt[i];
        base[i] = c ? atomicAdd(&bcursor[i], c) : 0;
        cnt[i] = 0;
    }
    __syncthreads();
#pragma unroll
    for (int u = 0; u < 16; ++u) {
        int e = e0 + u * 256 + t;
        if (e < N_EDGES) {
            int d = dst[e];
            int b = d >> 7;
            int pos = base[b] + atomicAdd(&cnt[b], 1);
            ebuf[pos] = ((unsigned int)(d & 127) << 17) | (unsigned int)src[e];
        }
    }
}

// per-bucket counting sort by local dst: row_start per node + ssrc sorted by dst.
// one block (256 thr) per bucket; all-LDS int atomics (native).
__global__ __launch_bounds__(256) void k_bsort(const unsigned int* __restrict__ ebuf,
                                               const int* __restrict__ bstart,
                                               int* __restrict__ row_start,
                                               int* __restrict__ ssrc) {
    __shared__ int h[128];      // histogram -> cursor
    __shared__ int sc[128];     // scan buffer
    const int b = blockIdx.x;
    const int t = threadIdx.x;
    const int eb = bstart[b], e1 = bstart[b + 1];
    if (t < 128) h[t] = 0;
    __syncthreads();
    for (int e = eb + t; e < e1; e += 256)
        atomicAdd(&h[ebuf[e] >> 17], 1);
    __syncthreads();
    if (t < 128) sc[t] = h[t];
    __syncthreads();
    for (int o = 1; o < 128; o <<= 1) {
        int add = 0;
        if (t < 128 && t >= o) add = sc[t - o];
        __syncthreads();
        if (t < 128) sc[t] += add;
        __syncthreads();
    }
    if (t < 128) {
        int excl = sc[t] - h[t];
        row_start[b * 128 + t] = eb + excl;
        h[t] = excl;            // becomes cursor
    }
    __syncthreads();
    for (int e = eb + t; e < e1; e += 256) {
        unsigned int pk = ebuf[e];
        int dl = pk >> 17;
        int pos = eb + atomicAdd(&h[dl], 1);
        ssrc[pos] = (int)(pk & 0x1ffffu);
    }
}

// ---------------- casts / weight packing ----------------

__global__ void k_cast_bf16(const float* __restrict__ in, unsigned short* __restrict__ out) {
    int i = blockIdx.x * blockDim.x + threadIdx.x;
    float4 v = *(const float4*)&in[(size_t)i * 4];
    uint2 o;
    o.x = (unsigned int)f2bf(v.x) | ((unsigned int)f2bf(v.y) << 16);
    o.y = (unsigned int)f2bf(v.z) | ((unsigned int)f2bf(v.w) << 16);
    *(uint2*)&out[(size_t)i * 4] = o;
}

__global__ void k_pack_w(const float* __restrict__ Wl, const float* __restrict__ Wr,
                         unsigned short* __restrict__ Wcat) {
    int idx = blockIdx.x * blockDim.x + threadIdx.x;
    float v = (idx < 16384) ? Wl[idx] : Wr[idx - 16384];
    Wcat[idx] = f2bf(v);
}

// ---------------- fused bf16 MFMA GEMM: [N x 128] @ [128 x 256] ----------------
template <bool OUT_F32>
__global__ __launch_bounds__(256) void k_gemm_mfma(
    const unsigned short* __restrict__ A,
    const unsigned short* __restrict__ Bt,
    const float* __restrict__ bias,
    unsigned short* __restrict__ Tout,
    void* __restrict__ Hout)
{
    const int wid = threadIdx.x >> 6;
    const int lane = threadIdx.x & 63;
    const int l15 = lane & 15, lg = lane >> 4;
    const int col_base = wid * 64;

    short8v bfrag[4][4];
#pragma unroll
    for (int cg = 0; cg < 4; ++cg)
#pragma unroll
        for (int ks = 0; ks < 4; ++ks)
            bfrag[cg][ks] = *(const short8v*)&Bt[(size_t)(col_base + cg * 16 + l15) * 128
                                                 + ks * 32 + lg * 8];
    float bv[4];
#pragma unroll
    for (int cg = 0; cg < 4; ++cg)
        bv[cg] = (wid >= 2) ? bias[(wid - 2) * 64 + cg * 16 + l15] : 0.0f;

    const int ntiles = (N_NODES + 63) / 64;
    for (int tile = blockIdx.x; tile < ntiles; tile += gridDim.x) {
        const int row0 = tile * 64;
        f32x4 acc[4][4];
#pragma unroll
        for (int rg = 0; rg < 4; ++rg)
#pragma unroll
            for (int cg = 0; cg < 4; ++cg)
                acc[rg][cg] = (f32x4){0.f, 0.f, 0.f, 0.f};

#pragma unroll
        for (int rg = 0; rg < 4; ++rg) {
            const int arow = row0 + rg * 16 + l15;
            short8v afrag[4];
            if (arow < N_NODES) {
#pragma unroll
                for (int ks = 0; ks < 4; ++ks)
                    afrag[ks] = *(const short8v*)&A[(size_t)arow * 128 + ks * 32 + lg * 8];
            } else {
#pragma unroll
                for (int ks = 0; ks < 4; ++ks) afrag[ks] = zero8();
            }
#pragma unroll
            for (int cg = 0; cg < 4; ++cg)
#pragma unroll
                for (int ks = 0; ks < 4; ++ks)
                    acc[rg][cg] = __builtin_amdgcn_mfma_f32_16x16x32_bf16(
                        afrag[ks], bfrag[cg][ks], acc[rg][cg], 0, 0, 0);
        }

        if (wid < 2) {
#pragma unroll
            for (int rg = 0; rg < 4; ++rg) {
                const int rbase = row0 + rg * 16 + lg * 4;
#pragma unroll
                for (int cg = 0; cg < 4; ++cg) {
                    const int col = col_base + cg * 16 + l15;
#pragma unroll
                    for (int i = 0; i < 4; ++i) {
                        int row = rbase + i;
                        if (row < N_NODES)
                            Tout[(size_t)row * 128 + col] = f2bf(acc[rg][cg][i]);
                    }
                }
            }
        } else {
#pragma unroll
            for (int rg = 0; rg < 4; ++rg) {
                const int rbase = row0 + rg * 16 + lg * 4;
#pragma unroll
                for (int cg = 0; cg < 4; ++cg) {
                    const int col = (wid - 2) * 64 + cg * 16 + l15;
#pragma unroll
                    for (int i = 0; i < 4; ++i) {
                        int row = rbase + i;
                        if (row < N_NODES) {
                            float v = acc[rg][cg][i] + bv[cg];
                            if (OUT_F32)
                                ((float*)Hout)[(size_t)row * 128 + col] = v;
                            else
                                ((unsigned short*)Hout)[(size_t)row * 128 + col] = f2bf(v);
                        }
                    }
                }
            }
        }
    }
}

// ---------------- pull aggregation: wave per node, register acc, 4-deep MLP ----------------
template <bool RELU, bool IOF32>
__global__ __launch_bounds__(256) void k_agg(
    const unsigned short* __restrict__ t_mat,   // [N][128] bf16
    const int* __restrict__ ssrc,               // edge srcs sorted by dst
    const int* __restrict__ row_start,          // [N..]+1
    void* __restrict__ io)                      // bf16 or f32, in-place update
{
    int w = (blockIdx.x * blockDim.x + threadIdx.x) >> 6;
    int lane = threadIdx.x & 63;
    if (w >= N_NODES) return;
    const int rs = row_start[w];
    const int re = row_start[w + 1];
    const int d = re - rs;
    float ax = 0.f, ay = 0.f;
    for (int q0 = rs; q0 < re; q0 += 64) {
        int nb = 0;
        if (q0 + lane < re) nb = ssrc[q0 + lane];
        const int m = min(64, re - q0);
        int q = 0;
        for (; q + 4 <= m; q += 4) {
            int j0 = __shfl(nb, q);
            int j1 = __shfl(nb, q + 1);
            int j2 = __shfl(nb, q + 2);
            int j3 = __shfl(nb, q + 3);
            unsigned int v0 = *(const unsigned int*)&t_mat[(size_t)j0 * 128 + lane * 2];
            unsigned int v1 = *(const unsigned int*)&t_mat[(size_t)j1 * 128 + lane * 2];
            unsigned int v2 = *(const unsigned int*)&t_mat[(size_t)j2 * 128 + lane * 2];
            unsigned int v3 = *(const unsigned int*)&t_mat[(size_t)j3 * 128 + lane * 2];
            ax += bf2f(v0 & 0xffffu) + bf2f(v1 & 0xffffu)
                + bf2f(v2 & 0xffffu) + bf2f(v3 & 0xffffu);
            ay += __uint_as_float(v0 & 0xffff0000u) + __uint_as_float(v1 & 0xffff0000u)
                + __uint_as_float(v2 & 0xffff0000u) + __uint_as_float(v3 & 0xffff0000u);
        }
        for (; q < m; ++q) {
            int j = __shfl(nb, q);
            unsigned int v = *(const unsigned int*)&t_mat[(size_t)j * 128 + lane * 2];
            ax += bf2f(v & 0xffffu);
            ay += __uint_as_float(v & 0xffff0000u);
        }
    }
    const float inv = 1.0f / (float)max(d, 1);
    if (IOF32) {
        float* o = (float*)io + (size_t)w * 128 + lane * 2;
        float2 cur = *(float2*)o;
        float rx = cur.x + inv * ax;
        float ry = cur.y + inv * ay;
        if (RELU) { rx = fmaxf(rx, 0.f); ry = fmaxf(ry, 0.f); }
        float2 res; res.x = rx; res.y = ry;
        *(float2*)o = res;
    } else {
        unsigned short* o = (unsigned short*)io + (size_t)w * 128 + lane * 2;
        unsigned int cur = *(unsigned int*)o;
        float rx = bf2f(cur & 0xffffu) + inv * ax;
        float ry = __uint_as_float(cur & 0xffff0000u) + inv * ay;
        if (RELU) { rx = fmaxf(rx, 0.f); ry = fmaxf(ry, 0.f); }
        *(unsigned int*)o = (unsigned int)f2bf(rx) | ((unsigned int)f2bf(ry) << 16);
    }
}

// ---------------- launch ----------------

extern "C" void kernel_launch(void* const* d_in, const int* in_sizes, int n_in,
                              void* d_out, int out_size, void* d_ws, size_t ws_size,
                              hipStream_t stream) {
    const float* x   = (const float*)d_in[0];
    const int*   ei  = (const int*)d_in[1];
    const float* W1l = (const float*)d_in[2];
    const float* W1r = (const float*)d_in[3];
    const float* b1  = (const float*)d_in[4];
    const float* W2l = (const float*)d_in[5];
    const float* W2r = (const float*)d_in[6];
    const float* b2  = (const float*)d_in[7];
    float* out = (float*)d_out;

    const int* src = ei;
    const int* dst = ei + N_EDGES;

    char* p = (char*)d_ws;
    auto alloc = [&](size_t bytes) {
        char* r = p;
        p += (bytes + 255) & ~(size_t)255;
        return r;
    };
    unsigned short* xb = (unsigned short*)alloc((size_t)N_NODES * D * 2);
    unsigned short* tb = (unsigned short*)alloc((size_t)N_NODES * D * 2);
    unsigned short* hx = (unsigned short*)alloc((size_t)N_NODES * D * 2);
    unsigned int*   ebuf    = (unsigned int*)alloc((size_t)N_EDGES * 4);
    int*   ssrc    = (int*)alloc((size_t)N_EDGES * 4);
    int*   bcnt    = (int*)alloc((NBUCK + 1) * sizeof(int));
    int*   bstart  = (int*)alloc((NBUCK + 1) * sizeof(int));
    int*   bcursor = (int*)alloc((NBUCK + 1) * sizeof(int));
    int*   row_start = (int*)alloc((size_t)(NBUCK * 128 + 1) * sizeof(int));
    unsigned short* wc1 = (unsigned short*)alloc(256 * 128 * 2);
    unsigned short* wc2 = (unsigned short*)alloc(256 * 128 * 2);

    // bucket build + per-bucket counting sort -> per-node CSR
    hipMemsetAsync(bcnt, 0, NBUCK * sizeof(int), stream);
    k_bcount<<<400, 256, 0, stream>>>(dst, bcnt);
    k_bscan<<<1, 1024, 0, stream>>>(bcnt, bstart, bcursor, row_start);
    k_bscatter<<<(N_EDGES + 4095) / 4096, 256, 0, stream>>>(src, dst, bcursor, ebuf);
    k_bsort<<<NBUCK, 256, 0, stream>>>(ebuf, bstart, row_start, ssrc);

    // casts + weight packing
    k_cast_bf16<<<(N_NODES * D / 4 + 255) / 256, 256, 0, stream>>>(x, xb);
    k_pack_w<<<128, 256, 0, stream>>>(W1l, W1r, wc1);
    k_pack_w<<<128, 256, 0, stream>>>(W2l, W2r, wc2);

    const int agg_grid = (N_NODES + 3) / 4;

    // layer 1
    k_gemm_mfma<false><<<640, 256, 0, stream>>>(xb, wc1, b1, tb, hx);
    k_agg<true, false><<<agg_grid, 256, 0, stream>>>(tb, ssrc, row_start, hx);

    // layer 2
    k_gemm_mfma<true><<<640, 256, 0, stream>>>(hx, wc2, b2, tb, out);
    k_agg<false, true><<<agg_grid, 256, 0, stream>>>(tb, ssrc, row_start, out);
}

// Round 5
// 247.937 us; speedup vs baseline: 11.2485x; 1.0885x over previous
//
#include <hip/hip_runtime.h>

#define N_NODES 100000
#define N_EDGES 1600000
#define D 128
#define NBUCK 782           // ceil(N_NODES / 128)
#define BSTRIDE 2560        // fixed slots per bucket (avg 2046, +5 sigma safe)

typedef __attribute__((ext_vector_type(8))) short short8v;
typedef __attribute__((ext_vector_type(4))) float f32x4;

__device__ __forceinline__ unsigned short f2bf(float f) {
    unsigned int u = __float_as_uint(f);
    unsigned int r = (u + 0x7fffu + ((u >> 16) & 1u)) >> 16;
    return (unsigned short)r;
}
__device__ __forceinline__ float bf2f(unsigned int lo16) {
    return __uint_as_float(lo16 << 16);
}
__device__ __forceinline__ short8v zero8() {
    short8v z = {0, 0, 0, 0, 0, 0, 0, 0};
    return z;
}

// ---------------- prep: pack weights bf16, zero bucket cursors ----------------
__global__ void k_prep(const float* __restrict__ W1l, const float* __restrict__ W1r,
                       const float* __restrict__ W2l, const float* __restrict__ W2r,
                       unsigned short* __restrict__ wc1, unsigned short* __restrict__ wc2,
                       int* __restrict__ gcnt) {
    int idx = blockIdx.x * 256 + threadIdx.x;
    if (idx < 16384)       wc1[idx] = f2bf(W1l[idx]);
    else if (idx < 32768)  wc1[idx] = f2bf(W1r[idx - 16384]);
    else if (idx < 49152)  wc2[idx - 32768] = f2bf(W2l[idx - 32768]);
    else if (idx < 65536)  wc2[idx - 32768] = f2bf(W2r[idx - 49152]);
    else if (idx - 65536 < NBUCK) gcnt[idx - 65536] = 0;
}

// ---------------- scatter edges into fixed-stride buckets (by dst>>7) ----------------
// payload = (dst&127)<<17 | src ; per-block LDS count -> one global atomic per bucket
__global__ __launch_bounds__(256) void k_bscatter(const int* __restrict__ src,
                                                  const int* __restrict__ dst,
                                                  int* __restrict__ gcnt,
                                                  unsigned int* __restrict__ ebuf) {
    __shared__ int cnt[NBUCK];
    __shared__ int base[NBUCK];
    const int t = threadIdx.x;
    const int e0 = blockIdx.x * 4096;
    for (int i = t; i < NBUCK; i += 256) cnt[i] = 0;
    __syncthreads();
#pragma unroll
    for (int u = 0; u < 16; ++u) {
        int e = e0 + u * 256 + t;
        if (e < N_EDGES) atomicAdd(&cnt[dst[e] >> 7], 1);
    }
    __syncthreads();
    for (int i = t; i < NBUCK; i += 256) {
        int c = cnt[i];
        base[i] = c ? atomicAdd(&gcnt[i], c) : 0;
        cnt[i] = 0;
    }
    __syncthreads();
#pragma unroll
    for (int u = 0; u < 16; ++u) {
        int e = e0 + u * 256 + t;
        if (e < N_EDGES) {
            int d = dst[e];
            int b = d >> 7;
            int pos = b * BSTRIDE + base[b] + atomicAdd(&cnt[b], 1);
            ebuf[pos] = ((unsigned int)(d & 127) << 17) | (unsigned int)src[e];
        }
    }
}

// ---------------- per-bucket counting sort by local dst ----------------
// row_start layout: 129 entries per bucket (start per node + bucket end)
__global__ __launch_bounds__(256) void k_bsort(const unsigned int* __restrict__ ebuf,
                                               const int* __restrict__ gcnt,
                                               int* __restrict__ row_start,
                                               int* __restrict__ ssrc) {
    __shared__ int h[128];
    __shared__ int sc[128];
    const int b = blockIdx.x;
    const int t = threadIdx.x;
    const int eb = b * BSTRIDE;
    const int n = gcnt[b];
    if (t < 128) h[t] = 0;
    __syncthreads();
    for (int e = t; e < n; e += 256)
        atomicAdd(&h[ebuf[eb + e] >> 17], 1);
    __syncthreads();
    if (t < 128) sc[t] = h[t];
    __syncthreads();
    for (int o = 1; o < 128; o <<= 1) {
        int add = 0;
        if (t < 128 && t >= o) add = sc[t - o];
        __syncthreads();
        if (t < 128) sc[t] += add;
        __syncthreads();
    }
    if (t < 128) {
        int excl = sc[t] - h[t];
        row_start[b * 129 + t] = eb + excl;
        h[t] = excl;            // becomes cursor
    }
    if (t == 0) row_start[b * 129 + 128] = eb + n;
    __syncthreads();
    for (int e = t; e < n; e += 256) {
        unsigned int pk = ebuf[eb + e];
        int dl = pk >> 17;
        int pos = eb + atomicAdd(&h[dl], 1);
        ssrc[pos] = (int)(pk & 0x1ffffu);
    }
}

// ---------------- fused bf16 MFMA GEMM: [N x 128] @ [128 x 256] ----------------
// A_F32: read f32 A, convert to bf16 fragments in-register (kills the cast pass)
template <bool A_F32, bool OUT_F32>
__global__ __launch_bounds__(256) void k_gemm_mfma(
    const void* __restrict__ Ain,
    const unsigned short* __restrict__ Bt,
    const float* __restrict__ bias,
    unsigned short* __restrict__ Tout,
    void* __restrict__ Hout)
{
    const int wid = threadIdx.x >> 6;
    const int lane = threadIdx.x & 63;
    const int l15 = lane & 15, lg = lane >> 4;
    const int col_base = wid * 64;

    short8v bfrag[4][4];
#pragma unroll
    for (int cg = 0; cg < 4; ++cg)
#pragma unroll
        for (int ks = 0; ks < 4; ++ks)
            bfrag[cg][ks] = *(const short8v*)&Bt[(size_t)(col_base + cg * 16 + l15) * 128
                                                 + ks * 32 + lg * 8];
    float bv[4];
#pragma unroll
    for (int cg = 0; cg < 4; ++cg)
        bv[cg] = (wid >= 2) ? bias[(wid - 2) * 64 + cg * 16 + l15] : 0.0f;

    const int ntiles = (N_NODES + 63) / 64;
    for (int tile = blockIdx.x; tile < ntiles; tile += gridDim.x) {
        const int row0 = tile * 64;
        f32x4 acc[4][4];
#pragma unroll
        for (int rg = 0; rg < 4; ++rg)
#pragma unroll
            for (int cg = 0; cg < 4; ++cg)
                acc[rg][cg] = (f32x4){0.f, 0.f, 0.f, 0.f};

#pragma unroll
        for (int rg = 0; rg < 4; ++rg) {
            const int arow = row0 + rg * 16 + l15;
            short8v afrag[4];
            if (arow < N_NODES) {
                if (A_F32) {
                    const float* Af = (const float*)Ain;
#pragma unroll
                    for (int ks = 0; ks < 4; ++ks) {
                        float4 p0 = *(const float4*)&Af[(size_t)arow * 128 + ks * 32 + lg * 8];
                        float4 p1 = *(const float4*)&Af[(size_t)arow * 128 + ks * 32 + lg * 8 + 4];
                        short8v f;
                        f[0] = (short)f2bf(p0.x); f[1] = (short)f2bf(p0.y);
                        f[2] = (short)f2bf(p0.z); f[3] = (short)f2bf(p0.w);
                        f[4] = (short)f2bf(p1.x); f[5] = (short)f2bf(p1.y);
                        f[6] = (short)f2bf(p1.z); f[7] = (short)f2bf(p1.w);
                        afrag[ks] = f;
                    }
                } else {
                    const unsigned short* Ab = (const unsigned short*)Ain;
#pragma unroll
                    for (int ks = 0; ks < 4; ++ks)
                        afrag[ks] = *(const short8v*)&Ab[(size_t)arow * 128 + ks * 32 + lg * 8];
                }
            } else {
#pragma unroll
                for (int ks = 0; ks < 4; ++ks) afrag[ks] = zero8();
            }
#pragma unroll
            for (int cg = 0; cg < 4; ++cg)
#pragma unroll
                for (int ks = 0; ks < 4; ++ks)
                    acc[rg][cg] = __builtin_amdgcn_mfma_f32_16x16x32_bf16(
                        afrag[ks], bfrag[cg][ks], acc[rg][cg], 0, 0, 0);
        }

        if (wid < 2) {
#pragma unroll
            for (int rg = 0; rg < 4; ++rg) {
                const int rbase = row0 + rg * 16 + lg * 4;
#pragma unroll
                for (int cg = 0; cg < 4; ++cg) {
                    const int col = col_base + cg * 16 + l15;
#pragma unroll
                    for (int i = 0; i < 4; ++i) {
                        int row = rbase + i;
                        if (row < N_NODES)
                            Tout[(size_t)row * 128 + col] = f2bf(acc[rg][cg][i]);
                    }
                }
            }
        } else {
#pragma unroll
            for (int rg = 0; rg < 4; ++rg) {
                const int rbase = row0 + rg * 16 + lg * 4;
#pragma unroll
                for (int cg = 0; cg < 4; ++cg) {
                    const int col = (wid - 2) * 64 + cg * 16 + l15;
#pragma unroll
                    for (int i = 0; i < 4; ++i) {
                        int row = rbase + i;
                        if (row < N_NODES) {
                            float v = acc[rg][cg][i] + bv[cg];
                            if (OUT_F32)
                                ((float*)Hout)[(size_t)row * 128 + col] = v;
                            else
                                ((unsigned short*)Hout)[(size_t)row * 128 + col] = f2bf(v);
                        }
                    }
                }
            }
        }
    }
}

// ---------------- pull aggregation: wave per node, register acc ----------------
template <bool RELU, bool IOF32>
__global__ __launch_bounds__(256) void k_agg(
    const unsigned short* __restrict__ t_mat,   // [N][128] bf16
    const int* __restrict__ ssrc,               // srcs sorted by dst (bucket-local CSR)
    const int* __restrict__ row_start,          // 129 per bucket
    void* __restrict__ io)                      // bf16 or f32, in-place update
{
    int w = (blockIdx.x * blockDim.x + threadIdx.x) >> 6;
    int lane = threadIdx.x & 63;
    if (w >= N_NODES) return;
    const int b = w >> 7, dl = w & 127;
    const int rs = row_start[b * 129 + dl];
    const int re = row_start[b * 129 + dl + 1];
    const int d = re - rs;
    float ax = 0.f, ay = 0.f;
    for (int q0 = rs; q0 < re; q0 += 64) {
        int nb = 0;
        if (q0 + lane < re) nb = ssrc[q0 + lane];
        const int m = min(64, re - q0);
        int q = 0;
        for (; q + 4 <= m; q += 4) {
            int j0 = __shfl(nb, q);
            int j1 = __shfl(nb, q + 1);
            int j2 = __shfl(nb, q + 2);
            int j3 = __shfl(nb, q + 3);
            unsigned int v0 = *(const unsigned int*)&t_mat[(size_t)j0 * 128 + lane * 2];
            unsigned int v1 = *(const unsigned int*)&t_mat[(size_t)j1 * 128 + lane * 2];
            unsigned int v2 = *(const unsigned int*)&t_mat[(size_t)j2 * 128 + lane * 2];
            unsigned int v3 = *(const unsigned int*)&t_mat[(size_t)j3 * 128 + lane * 2];
            ax += bf2f(v0 & 0xffffu) + bf2f(v1 & 0xffffu)
                + bf2f(v2 & 0xffffu) + bf2f(v3 & 0xffffu);
            ay += __uint_as_float(v0 & 0xffff0000u) + __uint_as_float(v1 & 0xffff0000u)
                + __uint_as_float(v2 & 0xffff0000u) + __uint_as_float(v3 & 0xffff0000u);
        }
        for (; q < m; ++q) {
            int j = __shfl(nb, q);
            unsigned int v = *(const unsigned int*)&t_mat[(size_t)j * 128 + lane * 2];
            ax += bf2f(v & 0xffffu);
            ay += __uint_as_float(v & 0xffff0000u);
        }
    }
    const float inv = 1.0f / (float)max(d, 1);
    if (IOF32) {
        float* o = (float*)io + (size_t)w * 128 + lane * 2;
        float2 cur = *(float2*)o;
        float rx = cur.x + inv * ax;
        float ry = cur.y + inv * ay;
        if (RELU) { rx = fmaxf(rx, 0.f); ry = fmaxf(ry, 0.f); }
        float2 res; res.x = rx; res.y = ry;
        *(float2*)o = res;
    } else {
        unsigned short* o = (unsigned short*)io + (size_t)w * 128 + lane * 2;
        unsigned int cur = *(unsigned int*)o;
        float rx = bf2f(cur & 0xffffu) + inv * ax;
        float ry = __uint_as_float(cur & 0xffff0000u) + inv * ay;
        if (RELU) { rx = fmaxf(rx, 0.f); ry = fmaxf(ry, 0.f); }
        *(unsigned int*)o = (unsigned int)f2bf(rx) | ((unsigned int)f2bf(ry) << 16);
    }
}

// ---------------- launch ----------------

extern "C" void kernel_launch(void* const* d_in, const int* in_sizes, int n_in,
                              void* d_out, int out_size, void* d_ws, size_t ws_size,
                              hipStream_t stream) {
    const float* x   = (const float*)d_in[0];
    const int*   ei  = (const int*)d_in[1];
    const float* W1l = (const float*)d_in[2];
    const float* W1r = (const float*)d_in[3];
    const float* b1  = (const float*)d_in[4];
    const float* W2l = (const float*)d_in[5];
    const float* W2r = (const float*)d_in[6];
    const float* b2  = (const float*)d_in[7];
    float* out = (float*)d_out;

    const int* src = ei;
    const int* dst = ei + N_EDGES;

    char* p = (char*)d_ws;
    auto alloc = [&](size_t bytes) {
        char* r = p;
        p += (bytes + 255) & ~(size_t)255;
        return r;
    };
    unsigned short* tb = (unsigned short*)alloc((size_t)N_NODES * D * 2);   // 25.6MB
    unsigned short* hx = (unsigned short*)alloc((size_t)N_NODES * D * 2);   // 25.6MB
    unsigned int*   ebuf = (unsigned int*)alloc((size_t)NBUCK * BSTRIDE * 4); // 8MB
    int*   ssrc      = (int*)alloc((size_t)NBUCK * BSTRIDE * 4);              // 8MB
    int*   gcnt      = (int*)alloc(NBUCK * sizeof(int));
    int*   row_start = (int*)alloc((size_t)NBUCK * 129 * sizeof(int));
    unsigned short* wc1 = (unsigned short*)alloc(256 * 128 * 2);
    unsigned short* wc2 = (unsigned short*)alloc(256 * 128 * 2);

    // prep (weights + cursor zero) -> scatter -> per-bucket sort
    k_prep<<<(65536 + NBUCK + 255) / 256, 256, 0, stream>>>(W1l, W1r, W2l, W2r, wc1, wc2, gcnt);
    k_bscatter<<<(N_EDGES + 4095) / 4096, 256, 0, stream>>>(src, dst, gcnt, ebuf);
    k_bsort<<<NBUCK, 256, 0, stream>>>(ebuf, gcnt, row_start, ssrc);

    const int agg_grid = (N_NODES + 3) / 4;

    // layer 1: [t|h_pre] = x @ [W1l;W1r]^T (+b1); h = relu(h_pre + mean t[nbrs])
    k_gemm_mfma<true, false><<<640, 256, 0, stream>>>(x, wc1, b1, tb, hx);
    k_agg<true, false><<<agg_grid, 256, 0, stream>>>(tb, ssrc, row_start, hx);

    // layer 2: [t|o_pre] = hx @ [W2l;W2r]^T (+b2); out = o_pre + mean t[nbrs]
    k_gemm_mfma<false, true><<<640, 256, 0, stream>>>(hx, wc2, b2, tb, out);
    k_agg<false, true><<<agg_grid, 256, 0, stream>>>(tb, ssrc, row_start, out);
}